// Round 1
// baseline (734.523 us; speedup 1.0000x reference)
//
#include <hip/hip_runtime.h>
#include <math.h>

#define L_SEQ 1024
#define BSZ 8
#define EMB 512
#define NH 8
#define DQ 64
#define BH (BSZ * NH)          // 64 head-batches
#define QKV_ROWS (3 * NH * DQ) // 1536
#define NEG_INF (-__builtin_inff())

// ---------------------------------------------------------------------------
// Kernel A: QKV projection. C[r,o] = sum_e emb[r,e]*W[o,e] + bias[o],
// r = l*BSZ + b. Scatter into Q/K/V laid out [bh = b*NH + h][l][d].
// o decomposes as h = o/192, c = o%192, sel = c/64 (0=Q,1=K,2=V), d = c%64.
// ---------------------------------------------------------------------------
__global__ __launch_bounds__(256) void qkv_gemm(
    const float* __restrict__ emb, const float* __restrict__ W,
    const float* __restrict__ bias,
    float* __restrict__ Q, float* __restrict__ Kp, float* __restrict__ V) {
  __shared__ __align__(16) float As[16][68];
  __shared__ __align__(16) float Bs[16][68];
  const int tid = threadIdx.x;
  const int tx = tid & 15, ty = tid >> 4;
  const int n0 = blockIdx.x * 64;  // o tile
  const int m0 = blockIdx.y * 64;  // row tile
  float acc[4][4] = {};
  for (int k0 = 0; k0 < EMB; k0 += 16) {
    const int r = tid >> 2;
    const int kk = (tid & 3) << 2;
    float4 a = *(const float4*)&emb[(size_t)(m0 + r) * EMB + k0 + kk];
    As[kk + 0][r] = a.x; As[kk + 1][r] = a.y;
    As[kk + 2][r] = a.z; As[kk + 3][r] = a.w;
    float4 b = *(const float4*)&W[(size_t)(n0 + r) * EMB + k0 + kk];
    Bs[kk + 0][r] = b.x; Bs[kk + 1][r] = b.y;
    Bs[kk + 2][r] = b.z; Bs[kk + 3][r] = b.w;
    __syncthreads();
#pragma unroll
    for (int k2 = 0; k2 < 16; ++k2) {
      float4 av = *(const float4*)&As[k2][ty * 4];
      float4 bv = *(const float4*)&Bs[k2][tx * 4];
      float am[4] = {av.x, av.y, av.z, av.w};
      float bm[4] = {bv.x, bv.y, bv.z, bv.w};
#pragma unroll
      for (int i = 0; i < 4; ++i)
#pragma unroll
        for (int j = 0; j < 4; ++j) acc[i][j] = fmaf(am[i], bm[j], acc[i][j]);
    }
    __syncthreads();
  }
#pragma unroll
  for (int i = 0; i < 4; ++i) {
    const int r = m0 + ty * 4 + i;
    const int l = r >> 3, bb = r & 7;
#pragma unroll
    for (int j = 0; j < 4; ++j) {
      const int o = n0 + tx * 4 + j;
      const int h = o / 192, c = o % 192;
      const int sel = c >> 6, d = c & 63;
      float val = acc[i][j] + bias[o];
      float* dst = (sel == 0) ? Q : (sel == 1) ? Kp : V;
      dst[((size_t)(bb * NH + h) * L_SEQ + l) * DQ + d] = val;
    }
  }
}

__device__ __forceinline__ float f4_elem(float4 v, int m) {
  return m == 0 ? v.x : m == 1 ? v.y : m == 2 ? v.z : v.w;
}

// ---------------------------------------------------------------------------
// Kernel B: flash attention with query-sum.
// attn_output[bh,:] = sum_l softmax_attn_output(l). Block = (qc, bh):
// 64 queries, online softmax over 16 m-tiles of 64 keys.
// KSs holds the K tile during S-GEMM, then is overwritten with S/P (saves LDS).
// Writes per-(bh,qc) partial sums; kernel C reduces them (deterministic).
// ---------------------------------------------------------------------------
__global__ __launch_bounds__(256) void flash_qsum(
    const float* __restrict__ Q, const float* __restrict__ K,
    const float* __restrict__ V, float* __restrict__ part) {
  const int qc = blockIdx.x;  // 16 query chunks
  const int bh = blockIdx.y;  // 64 head-batches
  __shared__ __align__(16) float Qs[64][68];
  __shared__ __align__(16) float KSs[64][68];  // K tile, then S/P tile
  __shared__ __align__(16) float Vs[64][68];
  __shared__ float Mrow[64], Zrow[64], Arow[64];
  const int tid = threadIdx.x;
  const int tx = tid & 15, ty = tid >> 4;

  {  // load Q tile [64 q][64 d]
    const int r = tid >> 2;
    const int cb = (tid & 3) * 16;
    const float* src = &Q[((size_t)bh * L_SEQ + qc * 64 + r) * DQ];
#pragma unroll
    for (int u = 0; u < 4; ++u)
      *(float4*)&Qs[r][cb + u * 4] = *(const float4*)&src[cb + u * 4];
  }
  if (tid < 64) { Mrow[tid] = NEG_INF; Zrow[tid] = 0.f; }
  float o_acc[4][4] = {};

  for (int mt = 0; mt < 16; ++mt) {
    __syncthreads();  // prev iteration's reads of KSs/Vs complete
    {  // load K,V tiles
      const int r = tid >> 2;
      const int cb = (tid & 3) * 16;
      const float* sk = &K[((size_t)bh * L_SEQ + mt * 64 + r) * DQ];
      const float* sv = &V[((size_t)bh * L_SEQ + mt * 64 + r) * DQ];
#pragma unroll
      for (int u = 0; u < 4; ++u) {
        *(float4*)&KSs[r][cb + u * 4] = *(const float4*)&sk[cb + u * 4];
        *(float4*)&Vs[r][cb + u * 4] = *(const float4*)&sv[cb + u * 4];
      }
    }
    __syncthreads();
    // S = Q*K^T (4x4 per thread, k-dim inner, float4 LDS reads)
    float s[4][4] = {};
#pragma unroll
    for (int kc = 0; kc < 64; kc += 4) {
      float4 a[4], b[4];
#pragma unroll
      for (int i = 0; i < 4; ++i) a[i] = *(const float4*)&Qs[ty * 4 + i][kc];
#pragma unroll
      for (int j = 0; j < 4; ++j) b[j] = *(const float4*)&KSs[tx * 4 + j][kc];
#pragma unroll
      for (int i = 0; i < 4; ++i)
#pragma unroll
        for (int j = 0; j < 4; ++j)
          s[i][j] += a[i].x * b[j].x + a[i].y * b[j].y + a[i].z * b[j].z +
                     a[i].w * b[j].w;
    }
    __syncthreads();  // everyone done reading K before overwrite with S
    // scale, mask (score==0 -> -inf), store S into KSs
#pragma unroll
    for (int i = 0; i < 4; ++i) {
      float4 sv;
      float v0 = s[i][0] * 0.125f, v1 = s[i][1] * 0.125f;
      float v2 = s[i][2] * 0.125f, v3 = s[i][3] * 0.125f;
      sv.x = (v0 == 0.f) ? NEG_INF : v0;
      sv.y = (v1 == 0.f) ? NEG_INF : v1;
      sv.z = (v2 == 0.f) ? NEG_INF : v2;
      sv.w = (v3 == 0.f) ? NEG_INF : v3;
      *(float4*)&KSs[ty * 4 + i][tx * 4] = sv;
    }
    __syncthreads();
    // row stats + P = exp(S - Mnew) (wave 0, one row per lane)
    if (tid < 64) {
      float mold = Mrow[tid];
      float tmax = NEG_INF;
#pragma unroll
      for (int c = 0; c < 16; ++c) {
        float4 r = *(const float4*)&KSs[tid][c * 4];
        tmax = fmaxf(tmax, fmaxf(fmaxf(r.x, r.y), fmaxf(r.z, r.w)));
      }
      float mnew = fmaxf(mold, tmax);
      float alpha = 1.f;
      if (mnew != NEG_INF) {
        alpha = __expf(mold - mnew);  // expf(-inf)=0 handles first tile
        float zs = 0.f;
#pragma unroll
        for (int c = 0; c < 16; ++c) {
          float4 r = *(const float4*)&KSs[tid][c * 4];
          r.x = __expf(r.x - mnew); r.y = __expf(r.y - mnew);
          r.z = __expf(r.z - mnew); r.w = __expf(r.w - mnew);
          *(float4*)&KSs[tid][c * 4] = r;
          zs += r.x + r.y + r.z + r.w;
        }
        Zrow[tid] = Zrow[tid] * alpha + zs;
        Mrow[tid] = mnew;
      } else {  // whole row masked so far: P = 0, state unchanged
#pragma unroll
        for (int c = 0; c < 16; ++c)
          *(float4*)&KSs[tid][c * 4] = make_float4(0.f, 0.f, 0.f, 0.f);
      }
      Arow[tid] = alpha;
    }
    __syncthreads();
    // O = O*alpha + P*V
    float al[4];
#pragma unroll
    for (int i = 0; i < 4; ++i) al[i] = Arow[ty * 4 + i];
#pragma unroll
    for (int i = 0; i < 4; ++i)
#pragma unroll
      for (int j = 0; j < 4; ++j) o_acc[i][j] *= al[i];
#pragma unroll
    for (int mc = 0; mc < 64; mc += 4) {
      float4 p[4];
#pragma unroll
      for (int i = 0; i < 4; ++i) p[i] = *(const float4*)&KSs[ty * 4 + i][mc];
#pragma unroll
      for (int mm = 0; mm < 4; ++mm) {
        float4 vv = *(const float4*)&Vs[mc + mm][tx * 4];
        float vm[4] = {vv.x, vv.y, vv.z, vv.w};
#pragma unroll
        for (int i = 0; i < 4; ++i) {
          float pm = f4_elem(p[i], mm);
#pragma unroll
          for (int j = 0; j < 4; ++j)
            o_acc[i][j] = fmaf(pm, vm[j], o_acc[i][j]);
        }
      }
    }
  }
  __syncthreads();  // last O-update reads of KSs done before reuse below
  // normalize rows by 1/Z and sum over this block's 64 queries
  float inv[4];
#pragma unroll
  for (int i = 0; i < 4; ++i) {
    float z = Zrow[ty * 4 + i];
    inv[i] = (z > 0.f) ? 1.f / z : 0.f;
  }
  float cs[4] = {0.f, 0.f, 0.f, 0.f};
#pragma unroll
  for (int i = 0; i < 4; ++i)
#pragma unroll
    for (int j = 0; j < 4; ++j) cs[j] += o_acc[i][j] * inv[i];
#pragma unroll
  for (int j = 0; j < 4; ++j) KSs[ty][tx * 4 + j] = cs[j];
  __syncthreads();
  if (tid < 64) {
    float a = 0.f;
#pragma unroll
    for (int t = 0; t < 16; ++t) a += KSs[t][tid];
    part[((size_t)bh * 16 + qc) * 64 + tid] = a;
  }
}

// ---------------------------------------------------------------------------
// Kernel C: sum 16 partials per bh, then GroupNorm over d=64 per (b,h).
// One wave (64 threads) per bh; shuffle reductions for mean/var.
// ---------------------------------------------------------------------------
__global__ __launch_bounds__(64) void finalize(
    const float* __restrict__ part, const float* __restrict__ gnw,
    const float* __restrict__ gnb, float* __restrict__ out) {
  const int bh = blockIdx.x;
  const int d = threadIdx.x;
  float v = 0.f;
#pragma unroll
  for (int qc = 0; qc < 16; ++qc) v += part[((size_t)bh * 16 + qc) * 64 + d];
  float s = v;
#pragma unroll
  for (int off = 32; off >= 1; off >>= 1) s += __shfl_xor(s, off, 64);
  float mean = s * (1.f / 64.f);
  float diff = v - mean;
  float sq = diff * diff;
#pragma unroll
  for (int off = 32; off >= 1; off >>= 1) sq += __shfl_xor(sq, off, 64);
  float var = sq * (1.f / 64.f);
  float o = diff * rsqrtf(var + 1e-5f);
  const int b = bh >> 3, h = bh & 7;
  out[(size_t)b * 512 + h * 64 + d] = o * gnw[h] + gnb[h];
}

extern "C" void kernel_launch(void* const* d_in, const int* in_sizes, int n_in,
                              void* d_out, int out_size, void* d_ws,
                              size_t ws_size, hipStream_t stream) {
  (void)in_sizes; (void)n_in; (void)out_size; (void)ws_size;
  const float* emb  = (const float*)d_in[0];
  const float* W    = (const float*)d_in[1];
  const float* bias = (const float*)d_in[2];
  const float* gnw  = (const float*)d_in[3];
  const float* gnb  = (const float*)d_in[4];
  float* out = (float*)d_out;
  float* ws = (float*)d_ws;
  const size_t per = (size_t)BH * L_SEQ * DQ;  // 4,194,304 floats
  float* Q = ws;
  float* K = ws + per;
  float* V = ws + 2 * per;
  float* part = ws + 3 * per;  // 64*16*64 floats

  qkv_gemm<<<dim3(QKV_ROWS / 64, (L_SEQ * BSZ) / 64), 256, 0, stream>>>(
      emb, W, bias, Q, K, V);
  flash_qsum<<<dim3(16, BH), 256, 0, stream>>>(Q, K, V, part);
  finalize<<<dim3(BH), 64, 0, stream>>>(part, gnw, gnb, out);
}

// Round 2
// 305.241 us; speedup vs baseline: 2.4064x; 2.4064x over previous
//
#include <hip/hip_runtime.h>
#include <hip/hip_bf16.h>
#include <math.h>

#define L_SEQ 1024
#define BSZ 8
#define EMB 512
#define NH 8
#define DQ 64
#define BH (BSZ * NH)          // 64 head-batches
#define QKV_ROWS (3 * NH * DQ) // 1536

typedef __attribute__((ext_vector_type(8))) short short8;   // 8 bf16 = 4 VGPR
typedef __attribute__((ext_vector_type(4))) float f32x4;

// ---------------------------------------------------------------------------
// Kernel A: QKV projection (f32 VALU GEMM, unchanged core).
// Epilogue: Q,K -> bf16 [bh][l][d]; V -> f32 [bh][l][d].
// ---------------------------------------------------------------------------
__global__ __launch_bounds__(256) void qkv_gemm(
    const float* __restrict__ emb, const float* __restrict__ W,
    const float* __restrict__ bias,
    __hip_bfloat16* __restrict__ Qb, __hip_bfloat16* __restrict__ Kb,
    float* __restrict__ V) {
  __shared__ __align__(16) float As[16][68];
  __shared__ __align__(16) float Bs[16][68];
  const int tid = threadIdx.x;
  const int tx = tid & 15, ty = tid >> 4;
  const int n0 = blockIdx.x * 64;  // o tile
  const int m0 = blockIdx.y * 64;  // row tile
  float acc[4][4] = {};
  for (int k0 = 0; k0 < EMB; k0 += 16) {
    const int r = tid >> 2;
    const int kk = (tid & 3) << 2;
    float4 a = *(const float4*)&emb[(size_t)(m0 + r) * EMB + k0 + kk];
    As[kk + 0][r] = a.x; As[kk + 1][r] = a.y;
    As[kk + 2][r] = a.z; As[kk + 3][r] = a.w;
    float4 b = *(const float4*)&W[(size_t)(n0 + r) * EMB + k0 + kk];
    Bs[kk + 0][r] = b.x; Bs[kk + 1][r] = b.y;
    Bs[kk + 2][r] = b.z; Bs[kk + 3][r] = b.w;
    __syncthreads();
#pragma unroll
    for (int k2 = 0; k2 < 16; ++k2) {
      float4 av = *(const float4*)&As[k2][ty * 4];
      float4 bv = *(const float4*)&Bs[k2][tx * 4];
      float am[4] = {av.x, av.y, av.z, av.w};
      float bm[4] = {bv.x, bv.y, bv.z, bv.w};
#pragma unroll
      for (int i = 0; i < 4; ++i)
#pragma unroll
        for (int j = 0; j < 4; ++j) acc[i][j] = fmaf(am[i], bm[j], acc[i][j]);
    }
    __syncthreads();
  }
#pragma unroll
  for (int i = 0; i < 4; ++i) {
    const int r = m0 + ty * 4 + i;
    const int l = r >> 3, bb = r & 7;
#pragma unroll
    for (int j = 0; j < 4; ++j) {
      const int o = n0 + tx * 4 + j;
      const int h = o / 192, c = o % 192;
      const int sel = c >> 6, d = c & 63;
      float val = acc[i][j] + bias[o];
      const size_t idx = ((size_t)(bb * NH + h) * L_SEQ + l) * DQ + d;
      if (sel == 2) {
        V[idx] = val;
      } else {
        __hip_bfloat16* dst = sel ? Kb : Qb;
        dst[idx] = __float2bfloat16(val);
      }
    }
  }
}

// ---------------------------------------------------------------------------
// Kernel B: two-pass MFMA attention-weight-sum.
// Block = (qc in 16, bh in 64), 256 thr = 4 waves, wave w owns 16 query rows.
// Pass 1: Z_l = sum_m exp(s_lm)  (no max subtraction: |s| ~ N(0,1), safe)
// Pass 2: cs[m] += sum_l exp(s_lm) / Z_l   (per-wave LDS colsum, reduced out)
// MFMA 16x16x32 bf16, f32 acc. Q-frags live in registers for the whole kernel.
// A-layout: lane holds A[m=lane&15][k=quad*8+j]; B same with n=lane&15.
// C/D-layout: col=lane&15, row=quad*4+reg  (m89/m91-verified).
// ---------------------------------------------------------------------------
__global__ __launch_bounds__(256) void attn_2pass(
    const __hip_bfloat16* __restrict__ Qb, const __hip_bfloat16* __restrict__ Kb,
    float* __restrict__ part) {
  const int qc = blockIdx.x;
  const int bh = blockIdx.y;
  const int tid = threadIdx.x;
  const int wave = tid >> 6, lane = tid & 63;
  const int quad = lane >> 4, col = lane & 15;

  __shared__ __align__(16) unsigned short Ks[64][72];  // 144B rows: 2-way=free
  __shared__ float cs[4][1024];                        // per-wave colsum, 16 KB

  for (int i = tid; i < 4 * 1024; i += 256) ((float*)cs)[i] = 0.f;

  // Q fragments: rows qc*64 + wave*16 + col, k = quad*8.. and 32+quad*8..
  const int qrow = qc * 64 + wave * 16 + col;
  const unsigned short* qptr =
      (const unsigned short*)&Qb[((size_t)bh * L_SEQ + qrow) * DQ];
  short8 qa0 = *(const short8*)&qptr[quad * 8];
  short8 qa1 = *(const short8*)&qptr[32 + quad * 8];

  float zacc[4] = {0.f, 0.f, 0.f, 0.f};
  float invz[4];

  // ---------------- PASS 1: Z per query row ----------------
  for (int st = 0; st < 16; ++st) {
    __syncthreads();
    for (int c = tid; c < 512; c += 256) {  // stage 64 keys x 64 d (8 KB)
      const int r = c >> 3, o = (c & 7) * 8;
      *(short8*)&Ks[r][o] = *(const short8*)
          &Kb[((size_t)bh * L_SEQ + st * 64 + r) * DQ + o];
    }
    __syncthreads();
#pragma unroll
    for (int sub = 0; sub < 4; ++sub) {
      const unsigned short* kp = &Ks[sub * 16 + col][0];
      short8 kb0 = *(const short8*)&kp[quad * 8];
      short8 kb1 = *(const short8*)&kp[32 + quad * 8];
      f32x4 s = {0.f, 0.f, 0.f, 0.f};
      s = __builtin_amdgcn_mfma_f32_16x16x32_bf16(qa0, kb0, s, 0, 0, 0);
      s = __builtin_amdgcn_mfma_f32_16x16x32_bf16(qa1, kb1, s, 0, 0, 0);
#pragma unroll
      for (int r = 0; r < 4; ++r) {
        float sc = s[r] * 0.125f;
        float p = (sc == 0.f) ? 0.f : __expf(sc);  // mask: score==0 -> weight 0
        zacc[r] += p;
      }
    }
  }
  // butterfly over the 16 lanes of each quad (cols of the rows quad*4+reg)
#pragma unroll
  for (int r = 0; r < 4; ++r) {
    float z = zacc[r];
#pragma unroll
    for (int off = 1; off <= 8; off <<= 1) z += __shfl_xor(z, off, 64);
    invz[r] = (z > 0.f) ? 1.f / z : 0.f;  // replicated across the quad
  }

  // ---------------- PASS 2: column sums of exp(s)*invz ----------------
  for (int st = 0; st < 16; ++st) {
    __syncthreads();
    for (int c = tid; c < 512; c += 256) {
      const int r = c >> 3, o = (c & 7) * 8;
      *(short8*)&Ks[r][o] = *(const short8*)
          &Kb[((size_t)bh * L_SEQ + st * 64 + r) * DQ + o];
    }
    __syncthreads();
#pragma unroll
    for (int sub = 0; sub < 4; ++sub) {
      const unsigned short* kp = &Ks[sub * 16 + col][0];
      short8 kb0 = *(const short8*)&kp[quad * 8];
      short8 kb1 = *(const short8*)&kp[32 + quad * 8];
      f32x4 s = {0.f, 0.f, 0.f, 0.f};
      s = __builtin_amdgcn_mfma_f32_16x16x32_bf16(qa0, kb0, s, 0, 0, 0);
      s = __builtin_amdgcn_mfma_f32_16x16x32_bf16(qa1, kb1, s, 0, 0, 0);
      float partial = 0.f;
#pragma unroll
      for (int r = 0; r < 4; ++r) {
        float sc = s[r] * 0.125f;
        float p = (sc == 0.f) ? 0.f : __expf(sc);
        partial = fmaf(p, invz[r], partial);
      }
      // sum the 4 quads (16 rows of this wave) holding the same key column
      partial += __shfl_xor(partial, 16, 64);
      partial += __shfl_xor(partial, 32, 64);
      if (quad == 0) cs[wave][st * 64 + sub * 16 + col] += partial;
    }
  }
  __syncthreads();
  for (int i = tid; i < 1024; i += 256)
    part[((size_t)bh * 16 + qc) * 1024 + i] =
        cs[0][i] + cs[1][i] + cs[2][i] + cs[3][i];
}

// ---------------------------------------------------------------------------
// Kernel C: aw[m] = sum_qc part; O[d] = sum_m aw[m]*V[m][d]; GroupNorm(d=64).
// One block (256 thr) per bh.
// ---------------------------------------------------------------------------
__global__ __launch_bounds__(256) void finalize2(
    const float* __restrict__ part, const float* __restrict__ V,
    const float* __restrict__ gnw, const float* __restrict__ gnb,
    float* __restrict__ out) {
  const int bh = blockIdx.x;
  const int tid = threadIdx.x;
  __shared__ float aw[1024];
  __shared__ float red[4][64];
  for (int m = tid; m < 1024; m += 256) {
    float a = 0.f;
#pragma unroll
    for (int qc = 0; qc < 16; ++qc)
      a += part[((size_t)bh * 16 + qc) * 1024 + m];
    aw[m] = a;
  }
  __syncthreads();
  const int d = tid & 63, g = tid >> 6;
  float acc = 0.f;
#pragma unroll 8
  for (int m = g * 256; m < (g + 1) * 256; ++m)
    acc = fmaf(aw[m], V[((size_t)bh * L_SEQ + m) * DQ + d], acc);
  red[g][d] = acc;
  __syncthreads();
  if (tid < 64) {
    float v = red[0][tid] + red[1][tid] + red[2][tid] + red[3][tid];
    float s = v;
#pragma unroll
    for (int off = 32; off >= 1; off >>= 1) s += __shfl_xor(s, off, 64);
    float mean = s * (1.f / 64.f);
    float diff = v - mean;
    float sq = diff * diff;
#pragma unroll
    for (int off = 32; off >= 1; off >>= 1) sq += __shfl_xor(sq, off, 64);
    float var = sq * (1.f / 64.f);
    float o = diff * rsqrtf(var + 1e-5f);
    const int b = bh >> 3, h = bh & 7;
    out[(size_t)b * 512 + h * 64 + tid] = o * gnw[h] + gnb[h];
  }
}

extern "C" void kernel_launch(void* const* d_in, const int* in_sizes, int n_in,
                              void* d_out, int out_size, void* d_ws,
                              size_t ws_size, hipStream_t stream) {
  (void)in_sizes; (void)n_in; (void)out_size; (void)ws_size;
  const float* emb  = (const float*)d_in[0];
  const float* W    = (const float*)d_in[1];
  const float* bias = (const float*)d_in[2];
  const float* gnw  = (const float*)d_in[3];
  const float* gnb  = (const float*)d_in[4];
  float* out = (float*)d_out;

  char* ws = (char*)d_ws;
  const size_t per = (size_t)BH * L_SEQ * DQ;  // 4,194,304 elements
  __hip_bfloat16* Qb = (__hip_bfloat16*)ws;                   // 8 MB
  __hip_bfloat16* Kb = (__hip_bfloat16*)(ws + per * 2);       // 8 MB
  float* V    = (float*)(ws + per * 4);                       // 16 MB
  float* part = (float*)(ws + per * 8);                       // 4 MB

  qkv_gemm<<<dim3(QKV_ROWS / 64, (L_SEQ * BSZ) / 64), 256, 0, stream>>>(
      emb, W, bias, Qb, Kb, V);
  attn_2pass<<<dim3(16, BH), 256, 0, stream>>>(Qb, Kb, part);
  finalize2<<<dim3(BH), 256, 0, stream>>>(part, V, gnw, gnb, out);
}

// Round 3
// 165.700 us; speedup vs baseline: 4.4328x; 1.8421x over previous
//
#include <hip/hip_runtime.h>
#include <hip/hip_bf16.h>
#include <math.h>

#define L_SEQ 1024
#define BSZ 8
#define EMB 512
#define NH 8
#define DQ 64
#define BH 64          // BSZ*NH
#define NQKV 1536      // 3*NH*DQ

typedef __attribute__((ext_vector_type(8))) short short8;   // 8 bf16 = 4 VGPR
typedef __attribute__((ext_vector_type(4))) float f32x4;

#define GPTR(x) ((const __attribute__((address_space(1))) void*)(x))
#define LPTR(x) ((__attribute__((address_space(3))) void*)(x))

__device__ __forceinline__ unsigned short bf16u(float x) {
  __hip_bfloat16 h = __float2bfloat16(x);
  return *(unsigned short*)&h;
}

// ---------------------------------------------------------------------------
// Kernel 0: f32 -> bf16 convert of emb (8192x512) and W (1536x512).
// 8 floats/thread, exact grid: (4194304+786432)/8 = 622592 = 2432*256.
// ---------------------------------------------------------------------------
__global__ __launch_bounds__(256) void to_bf16(
    const float* __restrict__ emb, const float* __restrict__ W,
    unsigned short* __restrict__ embB, unsigned short* __restrict__ WB) {
  const size_t t = (size_t)blockIdx.x * 256 + threadIdx.x;
  size_t base = t * 8;
  const float* src;
  unsigned short* dst;
  size_t off;
  if (base < (size_t)8192 * 512) { src = emb; dst = embB; off = base; }
  else { src = W; dst = WB; off = base - (size_t)8192 * 512; }
  float4 v0 = *(const float4*)&src[off];
  float4 v1 = *(const float4*)&src[off + 4];
  short8 o;
  o[0] = bf16u(v0.x); o[1] = bf16u(v0.y); o[2] = bf16u(v0.z); o[3] = bf16u(v0.w);
  o[4] = bf16u(v1.x); o[5] = bf16u(v1.y); o[6] = bf16u(v1.z); o[7] = bf16u(v1.w);
  *(short8*)&dst[off] = o;
}

// ---------------------------------------------------------------------------
// Kernel A: QKV projection, bf16 MFMA (m97 pattern).
// C[r,o] = sum_e embB[r,e]*WB[o,e] + bias[o], r = l*8+b, scatter to
// Q/K/V[bh=b*8+h][l][d] (all bf16). 128x128 block tile, BK=32,
// global_load_lds width=16 staging, 4 waves 2x2, 4x4 MFMA 16x16x32 each.
// C/D layout: row(m)=quad*4+reg, col(n)=lane&15 (m89-verified).
// ---------------------------------------------------------------------------
__global__ __launch_bounds__(256) void qkv_mfma(
    const unsigned short* __restrict__ A,   // embB [8192][512]
    const unsigned short* __restrict__ B,   // WB   [1536][512]
    const float* __restrict__ bias,
    unsigned short* __restrict__ Qb, unsigned short* __restrict__ Kb,
    unsigned short* __restrict__ Vb) {
  __shared__ __align__(16) unsigned short As[128][32];  // 8 KB, unpadded
  __shared__ __align__(16) unsigned short Bs[128][32];  // 8 KB
  const int tid = threadIdx.x;
  const int wave = tid >> 6, lane = tid & 63;
  const int quad = lane >> 4, col = lane & 15;
  const int wr = wave >> 1, wc = wave & 1;
  const int m0 = blockIdx.y * 128, n0 = blockIdx.x * 128;
  const int r16 = lane >> 2, q4 = lane & 3;  // 16 rows x 64B per instr

  f32x4 acc[4][4] = {};

  for (int kt = 0; kt < EMB; kt += 32) {
    __syncthreads();  // prev compute's LDS reads done
#pragma unroll
    for (int c = 0; c < 2; ++c) {
      const int rowA = (c * 4 + wave) * 16;
      __builtin_amdgcn_global_load_lds(
          GPTR(A + (size_t)(m0 + rowA + r16) * EMB + kt + q4 * 8),
          LPTR(&As[rowA][0]), 16, 0, 0);
      __builtin_amdgcn_global_load_lds(
          GPTR(B + (size_t)(n0 + rowA + r16) * EMB + kt + q4 * 8),
          LPTR(&Bs[rowA][0]), 16, 0, 0);
    }
    __syncthreads();  // vmcnt drain + barrier
    short8 af[4], bf[4];
#pragma unroll
    for (int i = 0; i < 4; ++i)
      af[i] = *(const short8*)&As[wr * 64 + i * 16 + col][quad * 8];
#pragma unroll
    for (int j = 0; j < 4; ++j)
      bf[j] = *(const short8*)&Bs[wc * 64 + j * 16 + col][quad * 8];
#pragma unroll
    for (int i = 0; i < 4; ++i)
#pragma unroll
      for (int j = 0; j < 4; ++j)
        acc[i][j] =
            __builtin_amdgcn_mfma_f32_16x16x32_bf16(af[i], bf[j], acc[i][j],
                                                    0, 0, 0);
  }

  // epilogue: bias + scatter. o depends only on (j, col).
#pragma unroll
  for (int j = 0; j < 4; ++j) {
    const int o = n0 + wc * 64 + j * 16 + col;
    const float bj = bias[o];
    const int h = o / 192;
    const int c2 = o - h * 192;
    const int sel = c2 >> 6, d = c2 & 63;
    unsigned short* dst = (sel == 0) ? Qb : (sel == 1) ? Kb : Vb;
#pragma unroll
    for (int i = 0; i < 4; ++i) {
      const int mrow = m0 + wr * 64 + i * 16 + quad * 4;
#pragma unroll
      for (int r = 0; r < 4; ++r) {
        const int row = mrow + r;
        const int l = row >> 3, bb = row & 7;
        dst[(((size_t)(bb * NH + h)) * L_SEQ + l) * DQ + d] =
            bf16u(acc[i][j][r] + bj);
      }
    }
  }
}

// ---------------------------------------------------------------------------
// Kernel B: two-pass MFMA attention-weight-sum (unchanged from R2).
// ---------------------------------------------------------------------------
__global__ __launch_bounds__(256) void attn_2pass(
    const unsigned short* __restrict__ Qb, const unsigned short* __restrict__ Kb,
    float* __restrict__ part) {
  const int qc = blockIdx.x;
  const int bh = blockIdx.y;
  const int tid = threadIdx.x;
  const int wave = tid >> 6, lane = tid & 63;
  const int quad = lane >> 4, col = lane & 15;

  __shared__ __align__(16) unsigned short Ks[64][72];  // 144B rows: 2-way=free
  __shared__ float cs[4][1024];

  for (int i = tid; i < 4 * 1024; i += 256) ((float*)cs)[i] = 0.f;

  const int qrow = qc * 64 + wave * 16 + col;
  const unsigned short* qptr = &Qb[((size_t)bh * L_SEQ + qrow) * DQ];
  short8 qa0 = *(const short8*)&qptr[quad * 8];
  short8 qa1 = *(const short8*)&qptr[32 + quad * 8];

  float zacc[4] = {0.f, 0.f, 0.f, 0.f};
  float invz[4];

  // ---------------- PASS 1: Z per query row ----------------
  for (int st = 0; st < 16; ++st) {
    __syncthreads();
    for (int c = tid; c < 512; c += 256) {
      const int r = c >> 3, o = (c & 7) * 8;
      *(short8*)&Ks[r][o] =
          *(const short8*)&Kb[((size_t)bh * L_SEQ + st * 64 + r) * DQ + o];
    }
    __syncthreads();
#pragma unroll
    for (int sub = 0; sub < 4; ++sub) {
      const unsigned short* kp = &Ks[sub * 16 + col][0];
      short8 kb0 = *(const short8*)&kp[quad * 8];
      short8 kb1 = *(const short8*)&kp[32 + quad * 8];
      f32x4 s = {0.f, 0.f, 0.f, 0.f};
      s = __builtin_amdgcn_mfma_f32_16x16x32_bf16(qa0, kb0, s, 0, 0, 0);
      s = __builtin_amdgcn_mfma_f32_16x16x32_bf16(qa1, kb1, s, 0, 0, 0);
#pragma unroll
      for (int r = 0; r < 4; ++r) {
        float sc = s[r] * 0.125f;
        float p = (sc == 0.f) ? 0.f : __expf(sc);
        zacc[r] += p;
      }
    }
  }
#pragma unroll
  for (int r = 0; r < 4; ++r) {
    float z = zacc[r];
#pragma unroll
    for (int off = 1; off <= 8; off <<= 1) z += __shfl_xor(z, off, 64);
    invz[r] = (z > 0.f) ? 1.f / z : 0.f;
  }

  // ---------------- PASS 2: colsums of exp(s)*invz ----------------
  for (int st = 0; st < 16; ++st) {
    __syncthreads();
    for (int c = tid; c < 512; c += 256) {
      const int r = c >> 3, o = (c & 7) * 8;
      *(short8*)&Ks[r][o] =
          *(const short8*)&Kb[((size_t)bh * L_SEQ + st * 64 + r) * DQ + o];
    }
    __syncthreads();
#pragma unroll
    for (int sub = 0; sub < 4; ++sub) {
      const unsigned short* kp = &Ks[sub * 16 + col][0];
      short8 kb0 = *(const short8*)&kp[quad * 8];
      short8 kb1 = *(const short8*)&kp[32 + quad * 8];
      f32x4 s = {0.f, 0.f, 0.f, 0.f};
      s = __builtin_amdgcn_mfma_f32_16x16x32_bf16(qa0, kb0, s, 0, 0, 0);
      s = __builtin_amdgcn_mfma_f32_16x16x32_bf16(qa1, kb1, s, 0, 0, 0);
      float partial = 0.f;
#pragma unroll
      for (int r = 0; r < 4; ++r) {
        float sc = s[r] * 0.125f;
        float p = (sc == 0.f) ? 0.f : __expf(sc);
        partial = fmaf(p, invz[r], partial);
      }
      partial += __shfl_xor(partial, 16, 64);
      partial += __shfl_xor(partial, 32, 64);
      if (quad == 0) cs[wave][st * 64 + sub * 16 + col] += partial;
    }
  }
  __syncthreads();
  for (int i = tid; i < 1024; i += 256)
    part[((size_t)bh * 16 + qc) * 1024 + i] =
        cs[0][i] + cs[1][i] + cs[2][i] + cs[3][i];
}

// ---------------------------------------------------------------------------
// Kernel C1: per-(bh, quarter) aw-reduce + partial O[d]. 256 blocks.
// ---------------------------------------------------------------------------
__global__ __launch_bounds__(256) void finalize_a(
    const float* __restrict__ part, const unsigned short* __restrict__ Vb,
    float* __restrict__ part2) {
  const int bh = blockIdx.x >> 2, g = blockIdx.x & 3;
  const int tid = threadIdx.x;
  __shared__ float aw[256];
  __shared__ float red[4][64];
  {
    const int m = g * 256 + tid;
    float a = 0.f;
#pragma unroll
    for (int qc = 0; qc < 16; ++qc)
      a += part[((size_t)bh * 16 + qc) * 1024 + m];
    aw[tid] = a;
  }
  __syncthreads();
  const int d = tid & 63, sub = tid >> 6;
  float acc = 0.f;
#pragma unroll 8
  for (int mm = 0; mm < 64; ++mm) {
    const int m = g * 256 + sub * 64 + mm;
    __hip_bfloat16 v;
    *(unsigned short*)&v = Vb[((size_t)bh * L_SEQ + m) * DQ + d];
    acc = fmaf(aw[sub * 64 + mm], __bfloat162float(v), acc);
  }
  red[sub][d] = acc;
  __syncthreads();
  if (tid < 64)
    part2[((size_t)bh * 4 + g) * 64 + tid] =
        red[0][tid] + red[1][tid] + red[2][tid] + red[3][tid];
}

// ---------------------------------------------------------------------------
// Kernel C2: reduce 4 partials + GroupNorm(d=64). One wave per bh.
// ---------------------------------------------------------------------------
__global__ __launch_bounds__(64) void finalize_b(
    const float* __restrict__ part2, const float* __restrict__ gnw,
    const float* __restrict__ gnb, float* __restrict__ out) {
  const int bh = blockIdx.x;
  const int d = threadIdx.x;
  float v = 0.f;
#pragma unroll
  for (int g = 0; g < 4; ++g) v += part2[((size_t)bh * 4 + g) * 64 + d];
  float s = v;
#pragma unroll
  for (int off = 32; off >= 1; off >>= 1) s += __shfl_xor(s, off, 64);
  float mean = s * (1.f / 64.f);
  float diff = v - mean;
  float sq = diff * diff;
#pragma unroll
  for (int off = 32; off >= 1; off >>= 1) sq += __shfl_xor(sq, off, 64);
  float var = sq * (1.f / 64.f);
  float o = diff * rsqrtf(var + 1e-5f);
  const int b = bh >> 3, h = bh & 7;
  out[(size_t)b * 512 + h * 64 + d] = o * gnw[h] + gnb[h];
}

extern "C" void kernel_launch(void* const* d_in, const int* in_sizes, int n_in,
                              void* d_out, int out_size, void* d_ws,
                              size_t ws_size, hipStream_t stream) {
  (void)in_sizes; (void)n_in; (void)out_size; (void)ws_size;
  const float* emb  = (const float*)d_in[0];
  const float* W    = (const float*)d_in[1];
  const float* bias = (const float*)d_in[2];
  const float* gnw  = (const float*)d_in[3];
  const float* gnb  = (const float*)d_in[4];
  float* out = (float*)d_out;

  char* ws = (char*)d_ws;
  const size_t perQ = (size_t)BH * L_SEQ * DQ;        // 4,194,304 elems
  unsigned short* embB = (unsigned short*)ws;                      // 8 MB
  unsigned short* WB   = (unsigned short*)(ws + 8u * 1024 * 1024); // 1.5 MB
  unsigned short* Qb   = (unsigned short*)(ws + 10u * 1024 * 1024);
  unsigned short* Kb   = Qb + perQ;
  unsigned short* Vb   = Kb + perQ;
  float* part  = (float*)(ws + 34u * 1024 * 1024);    // 4 MB
  float* part2 = (float*)(ws + 38u * 1024 * 1024);    // 64 KB

  to_bf16<<<dim3(2432), 256, 0, stream>>>(emb, W, embB, WB);
  qkv_mfma<<<dim3(NQKV / 128, 8192 / 128), 256, 0, stream>>>(
      embB, WB, bias, Qb, Kb, Vb);
  attn_2pass<<<dim3(16, BH), 256, 0, stream>>>(Qb, Kb, part);
  finalize_a<<<dim3(BH * 4), 256, 0, stream>>>(part, Vb, part2);
  finalize_b<<<dim3(BH), 64, 0, stream>>>(part2, gnw, gnb, out);
}